// Round 11
// baseline (191.875 us; speedup 1.0000x reference)
//
#include <hip/hip_runtime.h>
#include <cstddef>

#define NEDGES   800000
#define NRAD     32
#define MAXZ     100
#define NGRP     (NEDGES / 16)                   // 50000 groups of 16 edges
#define NBLK     384                             // 2 blocks/CU (512 thr, 54.4KB LDS)
#define WPB      8                               // waves per block
#define STRIDE   (NBLK * WPB)                    // 3072 waves total
#define T1_OFF   0
#define T2_OFF   (MAXZ * 128)                    // 12800 floats
#define WC_OFF   (2 * MAXZ * 128)                // 25600 floats
#define FB_OFF   (WC_OFF + NRAD * 128)           // 29696 floats (B-frags, 8KB)
#define PT_OFF   (FB_OFF + 2048)                 // 31744 floats (bf16 tables, 51.2KB)
#define ZP_OFF   (PT_OFF + 12800)                // 44544 floats, then 800000 ints

#define TROW     136                             // LDS table row stride (u16)

typedef __attribute__((ext_vector_type(8))) short bf16x8;
typedef __attribute__((ext_vector_type(4))) float f32x4;

__device__ inline unsigned short f2bf(float f) {            // RTNE f32->bf16
    unsigned u = __float_as_uint(f);
    u += 0x7FFFu + ((u >> 16) & 1u);
    return (unsigned short)(u >> 16);
}
__device__ inline float bflo(unsigned u) { return __uint_as_float(u << 16); }
__device__ inline float bfhi(unsigned u) { return __uint_as_float(u & 0xFFFF0000u); }
__device__ inline float silu(float v) {
    return v * __builtin_amdgcn_rcpf(1.f + __expf(-v));
}

// ---------------------------------------------------------------------------
// Prep A: fold weights into tables (f32 master copies in ws).
// ---------------------------------------------------------------------------
__global__ __launch_bounds__(128)
void prep_kernel(const float* __restrict__ embed_w,
                 const float* __restrict__ w_rbf,
                 const float* __restrict__ w_edge,
                 const float* __restrict__ b_edge,
                 float* __restrict__ ws) {
    const int d = threadIdx.x;
    const int b = blockIdx.x;
    if (b < MAXZ) {
        float a1 = b_edge[d];
        float a2 = 0.f;
        #pragma unroll 8
        for (int k = 0; k < 128; ++k) {
            const float e = embed_w[b * 128 + k];
            a1 = fmaf(e, w_edge[k * 128 + d], a1);
            a2 = fmaf(e, w_edge[(128 + k) * 128 + d], a2);
        }
        ws[T1_OFF + b * 128 + d] = a1;
        ws[T2_OFF + b * 128 + d] = a2;
    } else {
        const int q = b - MAXZ;
        float a = 0.f;
        #pragma unroll 8
        for (int m = 0; m < 128; ++m)
            a = fmaf(w_rbf[q * 128 + m], w_edge[(256 + m) * 128 + d], a);
        ws[WC_OFF + q * 128 + d] = a;
    }
}

// ---------------------------------------------------------------------------
// Prep B: Wc fragments in MFMA lane order. After the operand swap these are
// the *A* operand: A[i=n16][k=kh*8+j] = Wc[kh*8+j][16g+n16]. Same layout.
// ---------------------------------------------------------------------------
__global__ __launch_bounds__(512)
void prep_b_kernel(const float* __restrict__ ws_in, float* __restrict__ ws) {
    const int tid  = threadIdx.x;
    const int g    = tid >> 6;
    const int lane = tid & 63;
    const int n16  = lane & 15;
    const int kh   = lane >> 4;
    unsigned short* FB = (unsigned short*)(ws + FB_OFF);
    #pragma unroll
    for (int j = 0; j < 8; ++j)
        FB[(g * 64 + lane) * 8 + j] =
            f2bf(ws_in[WC_OFF + (kh * 8 + j) * 128 + 16 * g + n16]);
}

// ---------------------------------------------------------------------------
// Prep C: bf16 tables in NATURAL column order: PT[z][c] = bf16(T[z][c]),
// z in [0,200) (T1 rows then T2 rows).
// ---------------------------------------------------------------------------
__global__ __launch_bounds__(128)
void prep_pack_kernel(const float* __restrict__ ws_in, float* __restrict__ ws) {
    const int z = blockIdx.x;            // 0..199
    const int d = threadIdx.x;           // 0..127
    const float v = (z < MAXZ)
        ? ws_in[T1_OFF + z * 128 + d]
        : ws_in[T2_OFF + (z - MAXZ) * 128 + d];
    ((unsigned short*)(ws + PT_OFF))[z * 128 + d] = f2bf(v);
}

__global__ __launch_bounds__(256)
void zp_kernel(const int* __restrict__ x,
               const int* __restrict__ idx_i,
               const int* __restrict__ idx_j,
               int* __restrict__ zp) {
    const int e = blockIdx.x * 256 + threadIdx.x;
    zp[e] = (x[idx_j[e]] << 8) | x[idx_i[e]];
}

// ---------------------------------------------------------------------------
// Main. TRANSPOSED MFMA (operand swap): D[i=out-col][j=edge] so each lane
// owns ONE edge x 32 contiguous out-cols ->
//   - stores: 8 float4 instrs/group, each 16 rows x 64B contiguous (1KB)
//   - tables: per-lane z rows read from LDS as ds_read_b64 (padded stride)
// Prefetch depth 2 (named A/B buffers), 512-thread blocks -> 16 waves/CU.
// ---------------------------------------------------------------------------
__global__ __launch_bounds__(512, 4)
void edge_kernel(const float* __restrict__ rbf,
                 const int* __restrict__ zp,
                 const float* __restrict__ ws,
                 float* __restrict__ out) {
    __shared__ __align__(16) unsigned short sT[200 * TROW];   // 54400 B

    const int tid = threadIdx.x;
    {   // stage bf16 tables with pad: 200 rows x 16 uint4
        const uint4* __restrict__ src = (const uint4*)(ws + PT_OFF);
        for (int i = tid; i < 3200; i += 512) {
            const int z = i >> 4, p = i & 15;
            *(uint4*)((char*)sT + z * (TROW * 2) + p * 16) = src[i];
        }
    }
    __syncthreads();

    const int lane = tid & 63;
    const int wid  = tid >> 6;          // 0..7
    const int n16  = lane & 15;
    const int kh   = lane >> 4;

    const bf16x8* __restrict__ FB = (const bf16x8*)(ws + FB_OFF);
    bf16x8 bhi[8];
    #pragma unroll
    for (int g = 0; g < 8; ++g) {
        bhi[g] = FB[g * 64 + lane];
        asm volatile("" : "+v"(bhi[g]));         // pin: no remat
    }

    auto LOADG = [&](int g, f32x4& a0, f32x4& a4, int& zv) {
        if (g < NGRP) {
            const int eb = g * 16;
            const f32x4* ar = (const f32x4*)(rbf + (size_t)(eb + n16) * NRAD + kh * 8);
            a0 = ar[0]; a4 = ar[1];
            zv = zp[eb + n16];                   // per-lane edge's zp
        }
    };

    auto RUNG = [&](int g, f32x4 c0, f32x4 c4, int zpv) {
        const int ebase = g * 16;
        bf16x8 af;
        af[0] = (short)f2bf(c0.x); af[1] = (short)f2bf(c0.y);
        af[2] = (short)f2bf(c0.z); af[3] = (short)f2bf(c0.w);
        af[4] = (short)f2bf(c4.x); af[5] = (short)f2bf(c4.y);
        af[6] = (short)f2bf(c4.z); af[7] = (short)f2bf(c4.w);

        f32x4 acc[8];
        #pragma unroll
        for (int g8 = 0; g8 < 8; ++g8) {
            acc[g8] = (f32x4){0.f, 0.f, 0.f, 0.f};
            // SWAPPED operands: A = Wc^T frag, B = rbf^T frag
            acc[g8] = __builtin_amdgcn_mfma_f32_16x16x32_bf16(bhi[g8], af, acc[g8], 0, 0, 0);
        }

        const int zj = (zpv >> 8) & 0xFF;
        const int zi = zpv & 0xFF;
        const char* t1 = (const char*)sT + zj * (TROW * 2);
        const char* t2 = (const char*)sT + (MAXZ + zi) * (TROW * 2);
        float* __restrict__ op = out + (size_t)(ebase + n16) * 128 + kh * 4;

        #pragma unroll
        for (int g8 = 0; g8 < 8; ++g8) {
            const int off = (16 * g8 + kh * 4) * 2;
            const uint2 q1 = *(const uint2*)(t1 + off);
            const uint2 q2 = *(const uint2*)(t2 + off);
            f32x4 o;
            o.x = silu(acc[g8][0] + bflo(q1.x) + bflo(q2.x));
            o.y = silu(acc[g8][1] + bfhi(q1.x) + bfhi(q2.x));
            o.z = silu(acc[g8][2] + bflo(q1.y) + bflo(q2.y));
            o.w = silu(acc[g8][3] + bfhi(q1.y) + bfhi(q2.y));
            *(f32x4*)(op + 16 * g8) = o;
        }
    };

    int grp = blockIdx.x * WPB + wid;
    f32x4 a0A = {0,0,0,0}, a4A = {0,0,0,0}; int zvA = 0;
    f32x4 a0B = {0,0,0,0}, a4B = {0,0,0,0}; int zvB = 0;
    LOADG(grp,          a0A, a4A, zvA);
    LOADG(grp + STRIDE, a0B, a4B, zvB);

    while (grp < NGRP) {
        {
            const f32x4 c0 = a0A, c4 = a4A; const int cz = zvA;
            LOADG(grp + 2 * STRIDE, a0A, a4A, zvA);     // depth-2 prefetch
            RUNG(grp, c0, c4, cz);
        }
        grp += STRIDE;
        if (grp >= NGRP) break;
        {
            const f32x4 c0 = a0B, c4 = a4B; const int cz = zvB;
            LOADG(grp + 2 * STRIDE, a0B, a4B, zvB);
            RUNG(grp, c0, c4, cz);
        }
        grp += STRIDE;
    }
}

extern "C" void kernel_launch(void* const* d_in, const int* in_sizes, int n_in,
                              void* d_out, int out_size, void* d_ws, size_t ws_size,
                              hipStream_t stream) {
    const int*   x       = (const int*)d_in[0];
    const float* rbf     = (const float*)d_in[1];
    const int*   idx_i   = (const int*)d_in[2];
    const int*   idx_j   = (const int*)d_in[3];
    const float* embed_w = (const float*)d_in[4];
    const float* w_rbf   = (const float*)d_in[5];
    const float* w_edge  = (const float*)d_in[6];
    const float* b_edge  = (const float*)d_in[7];
    float* out = (float*)d_out;
    float* ws  = (float*)d_ws;
    int*   zp  = (int*)(ws + ZP_OFF);

    prep_kernel<<<MAXZ + NRAD, 128, 0, stream>>>(embed_w, w_rbf, w_edge, b_edge, ws);
    prep_b_kernel<<<1, 512, 0, stream>>>(ws, ws);
    prep_pack_kernel<<<2 * MAXZ, 128, 0, stream>>>(ws, ws);
    zp_kernel<<<NEDGES / 256, 256, 0, stream>>>(x, idx_i, idx_j, zp);
    edge_kernel<<<NBLK, 512, 0, stream>>>(rbf, zp, ws, out);
}